// Round 4
// baseline (3013.243 us; speedup 1.0000x reference)
//
#include <hip/hip_runtime.h>
#include <hip/hip_bf16.h>
#include <stdint.h>

#define R_ 128
#define N_ 512
#define DIM_ 128
#define H_ 8
#define DP_ 128
#define INNER_ 256
#define RD_ 4096   // R*DH

typedef __hip_bfloat16 bf16;

__device__ __forceinline__ float bf_lo(unsigned u) { return __uint_as_float(u << 16); }
__device__ __forceinline__ float bf_hi(unsigned u) { return __uint_as_float(u & 0xffff0000u); }

// ---------------------------------------------------------------------------
// Sentinel writer (interface diagnostics via absmax channel)
// ---------------------------------------------------------------------------
__global__ void k_sentinel(float* out, float v) { out[0] = v; }

// ---------------------------------------------------------------------------
// q_sw = x[0] @ Wq_sw + bq_sw  -> qsw [N][128] fp32   (once)
// ---------------------------------------------------------------------------
__global__ __launch_bounds__(128) void k_qsw(
    const float* __restrict__ x, const float* __restrict__ Wq_sw,
    const float* __restrict__ bq_sw, float* __restrict__ qsw)
{
    __shared__ float xr[128];
    const int n = blockIdx.x, t = threadIdx.x;
    xr[t] = x[(size_t)n * DIM_ + t];   // row r=0
    __syncthreads();
    float acc = bq_sw[t];
    for (int c = 0; c < 128; ++c) acc += xr[c] * Wq_sw[c * 128 + t];
    qsw[n * 128 + t] = acc;
}

// ---------------------------------------------------------------------------
// Per head: pair-bias LayerNorm + Wpair column h  -> dots [N][N] (pre-fill)
// ---------------------------------------------------------------------------
__global__ __launch_bounds__(256) void k_pb_h(
    const float* __restrict__ pb, const float* __restrict__ ln_g,
    const float* __restrict__ ln_b, const float* __restrict__ Wpair,
    float* __restrict__ dots, int h)
{
    __shared__ float sg[128], sb[128], wp[128];
    const int tid = threadIdx.x;
    if (tid < 128) { sg[tid] = ln_g[tid]; sb[tid] = ln_b[tid]; wp[tid] = Wpair[tid * 8 + h]; }
    __syncthreads();
    const int wave = tid >> 6, lane = tid & 63;
    const int flat = blockIdx.x * 4 + wave;    // i*N + j
    const float* pp = pb + (size_t)flat * DP_;
    float v0 = pp[lane], v1 = pp[lane + 64];
    float s = v0 + v1, ss = v0 * v0 + v1 * v1;
#pragma unroll
    for (int off = 32; off > 0; off >>= 1) {
        s  += __shfl_xor(s, off);
        ss += __shfl_xor(ss, off);
    }
    float mean = s * (1.0f / 128.0f);
    float var = ss * (1.0f / 128.0f) - mean * mean;
    float rs = rsqrtf(var + 1e-5f);
    float y0 = (v0 - mean) * rs * sg[lane] + sb[lane];
    float y1 = (v1 - mean) * rs * sg[lane + 64] + sb[lane + 64];
    float part = y0 * wp[lane] + y1 * wp[lane + 64];
#pragma unroll
    for (int off = 32; off > 0; off >>= 1) part += __shfl_xor(part, off);
    if (lane == 0) dots[flat] = part;
}

// ---------------------------------------------------------------------------
// Per head: sw[n][r] = dot16(qsw[n,h,:], x[r,n,:]@Wksw[:,h*16:]+b) * 0.25
// one thread per (n, r); fp32 end-to-end
// ---------------------------------------------------------------------------
__global__ __launch_bounds__(256) void k_sw_h(
    const float* __restrict__ x, const float* __restrict__ Wksw,
    const float* __restrict__ bksw, const float* __restrict__ qsw,
    float* __restrict__ sw, int h)
{
    const int idx = blockIdx.x * 256 + threadIdx.x;   // [0, 65536)
    const int n = idx >> 7, r = idx & 127;
    float acc[16];
#pragma unroll
    for (int d = 0; d < 16; ++d) acc[d] = bksw[h * 16 + d];
    const float* xr = x + (size_t)(r * N_ + n) * DIM_;
    for (int k = 0; k < 128; ++k) {
        float xv = xr[k];
        const float* wr = Wksw + k * 128 + h * 16;
#pragma unroll
        for (int d = 0; d < 16; ++d) acc[d] += xv * wr[d];
    }
    const float* qp = qsw + n * 128 + h * 16;
    float s = 0.0f;
#pragma unroll
    for (int d = 0; d < 16; ++d) s += acc[d] * qp[d];
    sw[n * 128 + r] = s * 0.25f;   // / sqrt(16 + 1e-8)
}

// ---------------------------------------------------------------------------
// softmax over r, in place on sw [N][R]
// ---------------------------------------------------------------------------
__global__ __launch_bounds__(128) void k_wrow2(float* __restrict__ sw)
{
    __shared__ float red[2];
    const int n = blockIdx.x, r = threadIdx.x;
    float s = sw[n * 128 + r];
    float m = s;
#pragma unroll
    for (int off = 32; off > 0; off >>= 1) m = fmaxf(m, __shfl_xor(m, off));
    if ((r & 63) == 0) red[r >> 6] = m;
    __syncthreads();
    m = fmaxf(red[0], red[1]);
    float e = __expf(s - m);
    float sum = e;
#pragma unroll
    for (int off = 32; off > 0; off >>= 1) sum += __shfl_xor(sum, off);
    __syncthreads();
    if ((r & 63) == 0) red[r >> 6] = sum;
    __syncthreads();
    sum = red[0] + red[1];
    sw[n * 128 + r] = e / sum;
}

// ---------------------------------------------------------------------------
// Simple 32-col projection per head: out = x @ W[:, col0:col0+32], bf16
// mode 0: out[(n*128 + r)*32 + d]   mode 1: out[(r*512 + n)*32 + d]
// ---------------------------------------------------------------------------
__global__ __launch_bounds__(256) void k_proj32(
    const float* __restrict__ x, const float* __restrict__ W,
    int ldw, int col0, bf16* __restrict__ out, int mode)
{
    __shared__ float xs[8][128];
    const int tid = threadIdx.x;
    const int row0 = blockIdx.x * 8;
#pragma unroll
    for (int l = 0; l < 4; ++l) {
        int idx = l * 256 + tid;
        int m = idx >> 7, k = idx & 127;
        xs[m][k] = x[(size_t)(row0 + m) * DIM_ + k];
    }
    __syncthreads();
    const int m = tid >> 5, d = tid & 31;
    float acc = 0.0f;
    for (int k = 0; k < 128; ++k) acc += xs[m][k] * W[k * ldw + col0 + d];
    const int rowg = row0 + m;
    const int r = rowg >> 9, n = rowg & (N_ - 1);
    size_t o = (mode == 0) ? ((size_t)n * 128 + r) * 32 + d
                           : ((size_t)r * 512 + n) * 32 + d;
    out[o] = __float2bfloat16(acc);
}

// ---------------------------------------------------------------------------
// Per head: dots[i][j] += scale * sum_{rd} wrow[i, rd>>5] * q[i][rd] * k[j][rd]
// 32x32 C-tile, grid (16,16) = 256 blocks, K=4096 in 64-chunks
// ---------------------------------------------------------------------------
__global__ __launch_bounds__(256) void k_dots2(
    const bf16* __restrict__ q_h, const bf16* __restrict__ k_h,
    const float* __restrict__ wrow, float* __restrict__ dots)
{
    __shared__ float as_t[64][34];   // [kk][i]
    __shared__ float bs_t[64][34];   // [kk][j]
    const int tid = threadIdx.x;
    const int jt = blockIdx.x, it = blockIdx.y;
    const int i0 = it * 32, j0 = jt * 32;
    const int tm = tid >> 4, tc = tid & 15;
    float acc[2][2] = {};

    for (int k0 = 0; k0 < RD_; k0 += 64) {
        const int i = tid >> 3, ck = tid & 7;
        const int rd = k0 + ck * 8;
        {
            uint4 u = *(const uint4*)(q_h + ((size_t)(i0 + i) << 12) + rd);
            float w = wrow[(i0 + i) * 128 + (rd >> 5)];
            as_t[ck * 8 + 0][i] = bf_lo(u.x) * w;
            as_t[ck * 8 + 1][i] = bf_hi(u.x) * w;
            as_t[ck * 8 + 2][i] = bf_lo(u.y) * w;
            as_t[ck * 8 + 3][i] = bf_hi(u.y) * w;
            as_t[ck * 8 + 4][i] = bf_lo(u.z) * w;
            as_t[ck * 8 + 5][i] = bf_hi(u.z) * w;
            as_t[ck * 8 + 6][i] = bf_lo(u.w) * w;
            as_t[ck * 8 + 7][i] = bf_hi(u.w) * w;
        }
        {
            uint4 u = *(const uint4*)(k_h + ((size_t)(j0 + i) << 12) + rd);
            bs_t[ck * 8 + 0][i] = bf_lo(u.x);
            bs_t[ck * 8 + 1][i] = bf_hi(u.x);
            bs_t[ck * 8 + 2][i] = bf_lo(u.y);
            bs_t[ck * 8 + 3][i] = bf_hi(u.y);
            bs_t[ck * 8 + 4][i] = bf_lo(u.z);
            bs_t[ck * 8 + 5][i] = bf_hi(u.z);
            bs_t[ck * 8 + 6][i] = bf_lo(u.w);
            bs_t[ck * 8 + 7][i] = bf_hi(u.w);
        }
        __syncthreads();
#pragma unroll 8
        for (int kk = 0; kk < 64; ++kk) {
            float2 a = *(const float2*)&as_t[kk][tm * 2];
            float2 b = *(const float2*)&bs_t[kk][tc * 2];
            acc[0][0] += a.x * b.x; acc[0][1] += a.x * b.y;
            acc[1][0] += a.y * b.x; acc[1][1] += a.y * b.y;
        }
        __syncthreads();
    }

    const float scale = 0.17677669529663689f;   // 32^-0.5
#pragma unroll
    for (int ii = 0; ii < 2; ++ii)
#pragma unroll
        for (int jj = 0; jj < 2; ++jj)
            dots[(size_t)(i0 + tm * 2 + ii) * N_ + j0 + tc * 2 + jj] += acc[ii][jj] * scale;
}

// ---------------------------------------------------------------------------
// row softmax over j, in place on dots [N][N]
// ---------------------------------------------------------------------------
__global__ __launch_bounds__(256) void k_smax(float* __restrict__ dots)
{
    __shared__ float red[4];
    const int i = blockIdx.x;
    const int t = threadIdx.x;
    float* p = dots + (size_t)i * N_;
    float a = p[t], b = p[t + 256];
    float m = fmaxf(a, b);
#pragma unroll
    for (int off = 32; off > 0; off >>= 1) m = fmaxf(m, __shfl_xor(m, off));
    if ((t & 63) == 0) red[t >> 6] = m;
    __syncthreads();
    m = fmaxf(fmaxf(red[0], red[1]), fmaxf(red[2], red[3]));
    float e0 = __expf(a - m), e1 = __expf(b - m);
    float s = e0 + e1;
#pragma unroll
    for (int off = 32; off > 0; off >>= 1) s += __shfl_xor(s, off);
    __syncthreads();
    if ((t & 63) == 0) red[t >> 6] = s;
    __syncthreads();
    s = red[0] + red[1] + red[2] + red[3];
    float inv = 1.0f / s;
    p[t] = e0 * inv;
    p[t + 256] = e1 * inv;
}

// ---------------------------------------------------------------------------
// Per head: om[r][i][h*32+d] = sum_j attn[i][j] * v_h[r][j][d]
// grid (8 it, 128 r); om (bf16) lives in d_out
// ---------------------------------------------------------------------------
__global__ __launch_bounds__(256) void k_av_h(
    const float* __restrict__ attn, const bf16* __restrict__ v_h,
    bf16* __restrict__ om, int h)
{
    __shared__ float as[64][66];   // [i][j]
    __shared__ float vs[64][34];   // [j][d]
    const int tid = threadIdx.x;
    const int it = blockIdx.x, r = blockIdx.y;
    const int i0 = it * 64;
    const int ti = tid >> 4, td = tid & 15;
    float acc[4][2] = {};

    for (int j0 = 0; j0 < N_; j0 += 64) {
#pragma unroll
        for (int l = 0; l < 4; ++l) {
            int idx = l * 256 + tid;
            int i = idx >> 4, j4 = idx & 15;
            float4 u = *(const float4*)(attn + (size_t)(i0 + i) * N_ + j0 + j4 * 4);
            float* d = &as[i][j4 * 4];
            d[0] = u.x; d[1] = u.y; d[2] = u.z; d[3] = u.w;
        }
        {
            int j = tid >> 2, ck = tid & 3;
            uint4 u = *(const uint4*)(v_h + ((size_t)r * N_ + j0 + j) * 32 + ck * 8);
            float* d = &vs[j][ck * 8];
            d[0] = bf_lo(u.x); d[1] = bf_hi(u.x); d[2] = bf_lo(u.y); d[3] = bf_hi(u.y);
            d[4] = bf_lo(u.z); d[5] = bf_hi(u.z); d[6] = bf_lo(u.w); d[7] = bf_hi(u.w);
        }
        __syncthreads();
#pragma unroll 8
        for (int jj = 0; jj < 64; jj += 2) {
            float2 b0 = *(const float2*)&vs[jj][td * 2];
            float2 b1 = *(const float2*)&vs[jj + 1][td * 2];
#pragma unroll
            for (int i = 0; i < 4; ++i) {
                float2 a = *(const float2*)&as[ti * 4 + i][jj];
                acc[i][0] += a.x * b0.x + a.y * b1.x;
                acc[i][1] += a.x * b0.y + a.y * b1.y;
            }
        }
        __syncthreads();
    }
#pragma unroll
    for (int ii = 0; ii < 4; ++ii) {
        bf16* op = om + ((size_t)r * N_ + i0 + ti * 4 + ii) * INNER_ + h * 32 + td * 2;
        op[0] = __float2bfloat16(acc[ii][0]);
        op[1] = __float2bfloat16(acc[ii][1]);
    }
}

// ---------------------------------------------------------------------------
// out = om @ Wout + b_out, IN PLACE on d_out (om bf16 -> out fp32).
// Block owns 64 full rows; om row bytes == out row bytes -> in-place safe.
// ---------------------------------------------------------------------------
__global__ __launch_bounds__(256) void k_final(
    const bf16* om, const float* __restrict__ Wout,
    const float* __restrict__ b_out, float* out)
{
    __shared__ float as[64][68];
    __shared__ float ws[64][132];
    const int tid = threadIdx.x;
    const int row0 = blockIdx.x * 64;
    const int tm = tid >> 5, tc = tid & 31;
    float acc[8][4] = {};

    for (int k0 = 0; k0 < INNER_; k0 += 64) {
#pragma unroll
        for (int l = 0; l < 2; ++l) {
            int idx = l * 256 + tid;
            int m = idx >> 3, ck = idx & 7;
            uint4 u = *(const uint4*)(om + (size_t)(row0 + m) * INNER_ + k0 + ck * 8);
            float* d = &as[m][ck * 8];
            d[0] = bf_lo(u.x); d[1] = bf_hi(u.x); d[2] = bf_lo(u.y); d[3] = bf_hi(u.y);
            d[4] = bf_lo(u.z); d[5] = bf_hi(u.z); d[6] = bf_lo(u.w); d[7] = bf_hi(u.w);
        }
#pragma unroll
        for (int l = 0; l < 8; ++l) {
            int idx = l * 256 + tid;
            int kk = idx >> 5, c4 = idx & 31;
            float4 u = *(const float4*)(Wout + (size_t)(k0 + kk) * DIM_ + c4 * 4);
            float* d = &ws[kk][c4 * 4];
            d[0] = u.x; d[1] = u.y; d[2] = u.z; d[3] = u.w;
        }
        __syncthreads();
        for (int kk = 0; kk < 64; kk += 2) {
            float4 b0 = *(const float4*)&ws[kk][tc * 4];
            float4 b1 = *(const float4*)&ws[kk + 1][tc * 4];
#pragma unroll
            for (int i = 0; i < 8; ++i) {
                float2 a = *(const float2*)&as[tm * 8 + i][kk];
                acc[i][0] += a.x * b0.x + a.y * b1.x;
                acc[i][1] += a.x * b0.y + a.y * b1.y;
                acc[i][2] += a.x * b0.z + a.y * b1.z;
                acc[i][3] += a.x * b0.w + a.y * b1.w;
            }
        }
        __syncthreads();
    }
#pragma unroll
    for (int ii = 0; ii < 8; ++ii) {
        int rowg = row0 + tm * 8 + ii;
#pragma unroll
        for (int jj = 0; jj < 4; ++jj) {
            int cg = tc * 4 + jj;
            out[(size_t)rowg * DIM_ + cg] = acc[ii][jj] + b_out[cg];
        }
    }
}

// ---------------------------------------------------------------------------
// Workspace arena — high-water mark 9,961,472 B (9.5 MiB):
//   [0        ..  1,048,576)  dots  [N][N] fp32 (pb prefill -> +qk -> softmax in place)
//   [1,048,576..  1,310,720)  sw    [N][R] fp32 (-> wrow in place)
//   [1,310,720..  1,572,864)  qsw   [N][128] fp32
//   [1,572,864..  5,767,168)  q_h   [N][R][32] bf16
//   [5,767,168..  9,961,472)  k_h   [N][R][32] bf16, later aliased by v_h [R][N][32]
// om (bf16, 33.55 MB) lives in d_out; k_final converts to fp32 in place.
// ---------------------------------------------------------------------------
extern "C" void kernel_launch(void* const* d_in, const int* in_sizes, int n_in,
                              void* d_out, int out_size, void* d_ws, size_t ws_size,
                              hipStream_t stream)
{
    // ---- interface guards: report anomalies through the absmax channel ----
    static const int exp_sizes[13] = {8388608, 33554432, 32768, 65536, 32768,
                                      128, 128, 128, 1024, 16384, 128, 16384, 128};
    const size_t WS_NEED = 9961472ULL;
    float sentinel = 0.0f;
    if (n_in != 13) sentinel = 5e7f;
    else {
        for (int i = 0; i < 13; ++i)
            if (in_sizes[i] != exp_sizes[i]) { sentinel = 1e6f * (float)(i + 1); break; }
    }
    if (sentinel == 0.0f && out_size != 8388608) sentinel = 6e7f;
    if (sentinel == 0.0f && ws_size < WS_NEED) sentinel = 1e8f + (float)ws_size;
    if (sentinel != 0.0f) {
        k_sentinel<<<1, 1, 0, stream>>>((float*)d_out, sentinel);
        return;
    }

    const float* x     = (const float*)d_in[0];
    const float* pair  = (const float*)d_in[1];
    const float* Wq    = (const float*)d_in[2];
    const float* Wkv   = (const float*)d_in[3];
    const float* Wout  = (const float*)d_in[4];
    const float* b_out = (const float*)d_in[5];
    const float* ln_g  = (const float*)d_in[6];
    const float* ln_b  = (const float*)d_in[7];
    const float* Wpair = (const float*)d_in[8];
    const float* Wq_sw = (const float*)d_in[9];
    const float* bq_sw = (const float*)d_in[10];
    const float* Wk_sw = (const float*)d_in[11];
    const float* bk_sw = (const float*)d_in[12];

    char* w = (char*)d_ws;
    float* dots = (float*)(w);
    float* sw   = (float*)(w + 1048576ULL);
    float* qsw  = (float*)(w + 1310720ULL);
    bf16*  q_h  = (bf16*)(w + 1572864ULL);
    bf16*  k_h  = (bf16*)(w + 5767168ULL);
    bf16*  v_h  = k_h;                     // aliases k_h (k dead after k_dots2)
    bf16*  om   = (bf16*)d_out;

    k_qsw<<<dim3(512), 128, 0, stream>>>(x, Wq_sw, bq_sw, qsw);

    for (int h = 0; h < H_; ++h) {
        k_pb_h  <<<dim3(65536),   256, 0, stream>>>(pair, ln_g, ln_b, Wpair, dots, h);
        k_sw_h  <<<dim3(256),     256, 0, stream>>>(x, Wk_sw, bk_sw, qsw, sw, h);
        k_wrow2 <<<dim3(512),     128, 0, stream>>>(sw);
        k_proj32<<<dim3(8192),    256, 0, stream>>>(x, Wq,  256, h * 32,       q_h, 0);
        k_proj32<<<dim3(8192),    256, 0, stream>>>(x, Wkv, 512, h * 32,       k_h, 0);
        k_dots2 <<<dim3(16, 16),  256, 0, stream>>>(q_h, k_h, sw, dots);
        k_smax  <<<dim3(512),     256, 0, stream>>>(dots);
        k_proj32<<<dim3(8192),    256, 0, stream>>>(x, Wkv, 512, 256 + h * 32, v_h, 1);
        k_av_h  <<<dim3(8, 128),  256, 0, stream>>>(dots, v_h, om, h);
    }

    k_final<<<dim3(1024), 256, 0, stream>>>(om, Wout, b_out, (float*)d_out);
}